// Round 6
// baseline (3898.573 us; speedup 1.0000x reference)
//
#include <hip/hip_runtime.h>
#include <hip/hip_cooperative_groups.h>

namespace cg = cooperative_groups;

#define N_TOT 4096
#define HIDN  1024
#define EMBD  256
#define VOC   1024
#define NSTEP 12

typedef __bf16 bf16;
typedef _Float16 h16;
typedef __bf16 bf16x8 __attribute__((ext_vector_type(8)));
typedef __bf16 bf16x4 __attribute__((ext_vector_type(4)));
typedef _Float16 h16x8 __attribute__((ext_vector_type(8)));
typedef float  f32x4  __attribute__((ext_vector_type(4)));

#define VMCNT(n) asm volatile("s_waitcnt vmcnt(" #n ")" ::: "memory")
#define MEMFENCE() asm volatile("" ::: "memory")

static __device__ __forceinline__ f32x4 mfma16(bf16x8 a, bf16x8 b, f32x4 c) {
  return __builtin_amdgcn_mfma_f32_16x16x32_bf16(a, b, c, 0, 0, 0);
}

// async global->LDS, 16B per lane. LDS dest is wave-uniform base + lane*16;
// global source is per-lane (pre-swizzled to realize the XOR-swizzled layout).
static __device__ __forceinline__ void gload16(const bf16* g, bf16* l) {
  __builtin_amdgcn_global_load_lds(
      (const __attribute__((address_space(1))) void*)g,
      (__attribute__((address_space(3))) void*)l, 16, 0, 0);
}

struct KArgs {
  const float *target, *gumbels, *sos;
  const float *bih, *bhh, *bout, *bemb;
  const float *Wih, *Whh, *Wout, *Wemb;
  float* out;
  bf16 *wih_b, *whh_b, *wout_b, *wemb_b;
  float* bias1;
  bf16 *hbuf0, *hbuf1, *ebuf;
  h16* lbuf;
};

// 128x128 tile, 8 waves (2x4), BK=64, 4-deep LDS pipeline, counted vmcnt.
template <bool TWO, int NT>
static __device__ __forceinline__ void pipe_gemm(
    const bf16* __restrict__ A0, const bf16* __restrict__ B0, int K0,
    const bf16* __restrict__ A1, const bf16* __restrict__ B1, int K1,
    bf16* lds, int m0, int n0, int w, int lane, f32x4 acc[4][2])
{
  const int wr = w >> 2, wc = w & 3;
  const int lr = lane & 15, lk = lane >> 4;
  const int srow = lane >> 3;
  const int scol = (((lane & 7) ^ srow) << 3);

  auto stage = [&](int t, int bsel) {
    const bf16 *A, *B; int K, k0;
    if (TWO && t < 4) { A = A0; B = B0; K = K0; k0 = t << 6; }
    else if (TWO)     { A = A1; B = B1; K = K1; k0 = (t - 4) << 6; }
    else              { A = A0; B = B0; K = K0; k0 = t << 6; }
    bf16* base = lds + bsel * 16384;
#pragma unroll
    for (int r = 0; r < 2; ++r)
      gload16(&A[(size_t)(m0 + w * 16 + r * 8 + srow) * K + k0 + scol],
              base + (w * 16 + r * 8) * 64);
#pragma unroll
    for (int r = 0; r < 2; ++r)
      gload16(&B[(size_t)(n0 + w * 16 + r * 8 + srow) * K + k0 + scol],
              base + 8192 + (w * 16 + r * 8) * 64);
  };

  stage(0, 0); stage(1, 1); stage(2, 2);
  VMCNT(8);                           // tile 0 landed (per-wave; older ops drain first)
  for (int t = 0; t < NT; ++t) {
    MEMFENCE();
    __builtin_amdgcn_s_barrier();     // all waves: tile t landed; buf[(t+3)&3] free
    MEMFENCE();
    if (t + 3 < NT) stage(t + 3, (t + 3) & 3);
    if (t <= NT - 4)      VMCNT(8);
    else if (t == NT - 3) VMCNT(4);
    else if (t == NT - 2) VMCNT(0);
    const bf16* Ab = lds + (t & 3) * 16384;
    const bf16* Bb = Ab + 8192;
#pragma unroll
    for (int kk = 0; kk < 2; ++kk) {
      bf16x8 af[4], bfr[2];
#pragma unroll
      for (int mi = 0; mi < 4; ++mi) {
        int row = wr * 64 + mi * 16 + lr;
        af[mi] = *(const bf16x8*)&Ab[row * 64 + ((((kk << 2) | lk) ^ (row & 7)) << 3)];
      }
#pragma unroll
      for (int ni = 0; ni < 2; ++ni) {
        int row = wc * 32 + ni * 16 + lr;
        bfr[ni] = *(const bf16x8*)&Bb[row * 64 + ((((kk << 2) | lk) ^ (row & 7)) << 3)];
      }
#pragma unroll
      for (int mi = 0; mi < 4; ++mi)
#pragma unroll
        for (int ni = 0; ni < 2; ++ni)
          acc[mi][ni] = mfma16(af[mi], bfr[ni], acc[mi][ni]);
    }
  }
}

__global__ __launch_bounds__(512)
void fused_rnn_kernel(KArgs a)
{
  cg::grid_group grid = cg::this_grid();
  __shared__ bf16 lds[4 * 16384];   // 128 KB

  const int tid = threadIdx.x;
  const int lane = tid & 63;
  const int w = tid >> 6;           // 0..7
  const int id = (blockIdx.x & 7) * 32 + (blockIdx.x >> 3);  // bijective XCD swizzle
  const int lr = lane & 15, lk = lane >> 4;

  // ===== phase 0: prep (cvt weights/target, e0 fill, bias sum) =====
  for (int q = blockIdx.x * 512 + tid; q < 1966336; q += 131072) {
    if (q < 1703936) {
      const float* s; bf16* d; int o;
      if (q < 65536)        { s = a.Wih;    d = a.wih_b;  o = q; }
      else if (q < 327680)  { s = a.Whh;    d = a.whh_b;  o = q - 65536; }
      else if (q < 589824)  { s = a.Wout;   d = a.wout_b; o = q - 327680; }
      else if (q < 655360)  { s = a.Wemb;   d = a.wemb_b; o = q - 589824; }
      else                  { s = a.target; d = a.hbuf0;  o = q - 655360; }
      f32x4 v = *(const f32x4*)&s[(size_t)o * 4];
      bf16x4 b; b[0] = (bf16)v.x; b[1] = (bf16)v.y; b[2] = (bf16)v.z; b[3] = (bf16)v.w;
      *(bf16x4*)&d[(size_t)o * 4] = b;
    } else if (q < 1966080) {
      int o = q - 1703936;
      f32x4 v = *(const f32x4*)&a.sos[(o & 63) * 4];
      bf16x4 b; b[0] = (bf16)v.x; b[1] = (bf16)v.y; b[2] = (bf16)v.z; b[3] = (bf16)v.w;
      *(bf16x4*)&a.ebuf[(size_t)o * 4] = b;
    } else {
      int o = q - 1966080;
      f32x4 x = *(const f32x4*)&a.bih[o * 4];
      f32x4 c = *(const f32x4*)&a.bhh[o * 4];
      f32x4 r; r.x = x.x + c.x; r.y = x.y + c.y; r.z = x.z + c.z; r.w = x.w + c.w;
      *(f32x4*)&a.bias1[o * 4] = r;
    }
  }
  __threadfence();
  grid.sync();

  const int wr = w >> 2, wc = w & 3;
  const int m0 = (id >> 3) * 128;   // 32 m-tiles
  const int n0 = (id & 7) * 128;    // 8 n-tiles

  for (int t = 0; t < NSTEP; ++t) {
    const bf16* hp = (t & 1) ? a.hbuf1 : a.hbuf0;
    bf16* hn = (t & 1) ? a.hbuf0 : a.hbuf1;

    // ===== phase 1: h = tanh(e@Wih^T + hp@Whh^T + bias) =====
    {
      f32x4 acc[4][2] = {};
      pipe_gemm<true, 20>(a.ebuf, a.wih_b, EMBD, hp, a.whh_b, HIDN,
                          lds, m0, n0, w, lane, acc);
#pragma unroll
      for (int mi = 0; mi < 4; ++mi) {
        int rowb = m0 + wr * 64 + mi * 16 + lk * 4;
#pragma unroll
        for (int ni = 0; ni < 2; ++ni) {
          int col = n0 + wc * 32 + ni * 16 + lr;
          float bs = a.bias1[col];
#pragma unroll
          for (int j = 0; j < 4; ++j)
            hn[(size_t)(rowb + j) * HIDN + col] = (bf16)tanhf(acc[mi][ni][j] + bs);
        }
      }
    }
    __threadfence();
    grid.sync();

    // ===== phase 2: logits = h@Wout^T + b_out -> fp16 lbuf =====
    {
      f32x4 acc[4][2] = {};
      pipe_gemm<false, 16>(hn, a.wout_b, HIDN, nullptr, nullptr, 0,
                           lds, m0, n0, w, lane, acc);
#pragma unroll
      for (int mi = 0; mi < 4; ++mi) {
        int rowb = m0 + wr * 64 + mi * 16 + lk * 4;
#pragma unroll
        for (int ni = 0; ni < 2; ++ni) {
          int col = n0 + wc * 32 + ni * 16 + lr;
          float bs = a.bout[col];
#pragma unroll
          for (int j = 0; j < 4; ++j) {
            int row = rowb + j;
            a.lbuf[(size_t)row * VOC + col] = (h16)(acc[mi][ni][j] + bs);
          }
        }
      }
    }
    __threadfence();
    grid.sync();

    // ===== phase 3: softmax((l+g)) -> fp32 out + e_next = x@Wemb^T + b_emb =====
    {
      bf16* xs = lds;                 // 16*1032 bf16, aliases GEMM LDS
      const int r0 = id * 16;
      const float* gum = a.gumbels + (size_t)t * N_TOT * VOC;

      for (int rr = 0; rr < 2; ++rr) {
        int r = w + rr * 8;
        const h16* lrow = a.lbuf + (size_t)(r0 + r) * VOC;
        const float* grow = gum + (size_t)(r0 + r) * VOC;
        float s[16];
        float m = -1e30f;
#pragma unroll
        for (int i = 0; i < 2; ++i) {
          h16x8 lv = *(const h16x8*)&lrow[i * 512 + lane * 8];
          f32x4 g0 = *(const f32x4*)&grow[i * 512 + lane * 8];
          f32x4 g1 = *(const f32x4*)&grow[i * 512 + lane * 8 + 4];
#pragma unroll
          for (int j = 0; j < 4; ++j) {
            float f0 = (float)lv[j] + g0[j];
            float f1 = (float)lv[4 + j] + g1[j];
            s[i * 8 + j] = f0; s[i * 8 + 4 + j] = f1;
            m = fmaxf(m, fmaxf(f0, f1));
          }
        }
#pragma unroll
        for (int off = 32; off; off >>= 1) m = fmaxf(m, __shfl_xor(m, off));
        float sum = 0.f;
#pragma unroll
        for (int i = 0; i < 16; ++i) { s[i] = __expf(s[i] - m); sum += s[i]; }
#pragma unroll
        for (int off = 32; off; off >>= 1) sum += __shfl_xor(sum, off);
        float inv = 1.0f / sum;
        float* orow = a.out + ((size_t)(r0 + r) * NSTEP + t) * VOC;
#pragma unroll
        for (int i = 0; i < 2; ++i) {
          f32x4 v0, v1;
          bf16x8 bv;
#pragma unroll
          for (int j = 0; j < 4; ++j) {
            float x0 = s[i * 8 + j] * inv;
            float x1 = s[i * 8 + 4 + j] * inv;
            v0[j] = x0; v1[j] = x1;
            bv[j] = (bf16)x0; bv[4 + j] = (bf16)x1;
          }
          *(f32x4*)&orow[i * 512 + lane * 8] = v0;
          *(f32x4*)&orow[i * 512 + lane * 8 + 4] = v1;
          *(bf16x8*)&xs[r * 1032 + i * 512 + lane * 8] = bv;
        }
      }
      __syncthreads();

      f32x4 acc[2] = {};
      for (int k0 = 0; k0 < VOC; k0 += 32) {
        bf16x8 av = *(bf16x8*)&xs[lr * 1032 + k0 + lk * 8];
#pragma unroll
        for (int ni = 0; ni < 2; ++ni) {
          int col = w * 32 + ni * 16 + lr;
          bf16x8 b = *(const bf16x8*)&a.wemb_b[(size_t)col * VOC + k0 + lk * 8];
          acc[ni] = mfma16(av, b, acc[ni]);
        }
      }
#pragma unroll
      for (int ni = 0; ni < 2; ++ni) {
        int col = w * 32 + ni * 16 + lr;
        float bb = a.bemb[col];
#pragma unroll
        for (int j = 0; j < 4; ++j) {
          int n = r0 + lk * 4 + j;
          a.ebuf[(size_t)n * EMBD + col] = (bf16)(acc[ni][j] + bb);
        }
      }
    }
    __threadfence();
    grid.sync();
  }
}

// ---------------- launch ----------------

extern "C" void kernel_launch(void* const* d_in, const int* in_sizes, int n_in,
                              void* d_out, int out_size, void* d_ws, size_t ws_size,
                              hipStream_t stream) {
  char* ws = (char*)d_ws;
  KArgs a;
  a.target  = (const float*)d_in[0];
  a.gumbels = (const float*)d_in[1];
  a.sos     = (const float*)d_in[2];
  a.Wih     = (const float*)d_in[3];
  a.bih     = (const float*)d_in[4];
  a.Whh     = (const float*)d_in[5];
  a.bhh     = (const float*)d_in[6];
  a.Wout    = (const float*)d_in[7];
  a.bout    = (const float*)d_in[8];
  a.Wemb    = (const float*)d_in[9];
  a.bemb    = (const float*)d_in[10];
  a.out     = (float*)d_out;
  a.wih_b   = (bf16*)(ws);                // 512 KB
  a.whh_b   = (bf16*)(ws + (1u << 20));   // 2 MB
  a.wout_b  = (bf16*)(ws + (3u << 20));   // 2 MB
  a.wemb_b  = (bf16*)(ws + (5u << 20));   // 512 KB
  a.bias1   = (float*)(ws + (6u << 20));  // 4 KB
  a.hbuf0   = (bf16*)(ws + (7u << 20));   // 8 MB
  a.hbuf1   = (bf16*)(ws + (15u << 20));  // 8 MB
  a.ebuf    = (bf16*)(ws + (23u << 20));  // 2 MB
  a.lbuf    = (h16*) (ws + (25u << 20));  // 8 MB

  void* params[] = {(void*)&a};
  hipLaunchCooperativeKernel(fused_rnn_kernel, dim3(256), dim3(512), params, 0, stream);
}

// Round 7
// 655.130 us; speedup vs baseline: 5.9508x; 5.9508x over previous
//
#include <hip/hip_runtime.h>

#define N_TOT 4096
#define HIDN  1024
#define EMBD  256
#define VOC   1024
#define NSTEP 12

typedef __bf16 bf16;
typedef _Float16 h16;
typedef __bf16 bf16x8 __attribute__((ext_vector_type(8)));
typedef __bf16 bf16x4 __attribute__((ext_vector_type(4)));
typedef _Float16 h16x8 __attribute__((ext_vector_type(8)));
typedef float  f32x4  __attribute__((ext_vector_type(4)));

#define VMCNT(n) asm volatile("s_waitcnt vmcnt(" #n ")" ::: "memory")
#define MEMFENCE() asm volatile("" ::: "memory")

static __device__ __forceinline__ f32x4 mfma16(bf16x8 a, bf16x8 b, f32x4 c) {
  return __builtin_amdgcn_mfma_f32_16x16x32_bf16(a, b, c, 0, 0, 0);
}

// async global->LDS, 16B per lane. LDS dest is wave-uniform base + lane*16;
// global source is per-lane (pre-swizzled to realize the XOR-swizzled layout).
static __device__ __forceinline__ void gload16(const bf16* g, bf16* l) {
  __builtin_amdgcn_global_load_lds(
      (const __attribute__((address_space(1))) void*)g,
      (__attribute__((address_space(3))) void*)l, 16, 0, 0);
}

// ---------------- fused prep kernel ----------------

__global__ void prep_kernel(const float* __restrict__ Wih, const float* __restrict__ Whh,
                            const float* __restrict__ Wout, const float* __restrict__ Wemb,
                            const float* __restrict__ target, const float* __restrict__ sos,
                            const float* __restrict__ bih, const float* __restrict__ bhh,
                            bf16* __restrict__ wih_b, bf16* __restrict__ whh_b,
                            bf16* __restrict__ wout_b, bf16* __restrict__ wemb_b,
                            bf16* __restrict__ hbuf, bf16* __restrict__ ebuf,
                            float* __restrict__ bias1) {
  for (int q = blockIdx.x * blockDim.x + threadIdx.x; q < 1966336;
       q += blockDim.x * gridDim.x) {
    if (q < 1703936) {
      const float* s; bf16* d; int o;
      if (q < 65536)        { s = Wih;    d = wih_b;  o = q; }
      else if (q < 327680)  { s = Whh;    d = whh_b;  o = q - 65536; }
      else if (q < 589824)  { s = Wout;   d = wout_b; o = q - 327680; }
      else if (q < 655360)  { s = Wemb;   d = wemb_b; o = q - 589824; }
      else                  { s = target; d = hbuf;   o = q - 655360; }
      f32x4 v = *(const f32x4*)&s[(size_t)o * 4];
      bf16x4 b; b[0] = (bf16)v.x; b[1] = (bf16)v.y; b[2] = (bf16)v.z; b[3] = (bf16)v.w;
      *(bf16x4*)&d[(size_t)o * 4] = b;
    } else if (q < 1966080) {
      int o = q - 1703936;
      f32x4 v = *(const f32x4*)&sos[(o & 63) * 4];
      bf16x4 b; b[0] = (bf16)v.x; b[1] = (bf16)v.y; b[2] = (bf16)v.z; b[3] = (bf16)v.w;
      *(bf16x4*)&ebuf[(size_t)o * 4] = b;
    } else {
      int o = q - 1966080;
      f32x4 a = *(const f32x4*)&bih[o * 4];
      f32x4 c = *(const f32x4*)&bhh[o * 4];
      f32x4 r; r.x = a.x + c.x; r.y = a.y + c.y; r.z = a.z + c.z; r.w = a.w + c.w;
      *(f32x4*)&bias1[o * 4] = r;
    }
  }
}

// ===== shared GEMM core: 128x64 tile, 4 waves (2x2), BK=64, 3-deep pipeline =====
// LDS per buffer: A 128x64 (16KB) + B 64x64 (8KB) = 24KB; 3 buffers = 72KB -> 2 blocks/CU.

template <bool TWO, int NT>
static __device__ __forceinline__ void pipe_gemm(
    const bf16* __restrict__ A0, const bf16* __restrict__ B0, int K0,
    const bf16* __restrict__ A1, const bf16* __restrict__ B1, int K1,
    bf16* lds, int m0, int n0, int w, int lane, f32x4 acc[4][2])
{
  const int wr = w >> 1, wc = w & 1;
  const int lr = lane & 15, lk = lane >> 4;
  const int srow = lane >> 3;
  const int scol = (((lane & 7) ^ srow) << 3);

  auto stage = [&](int t, int bsel) {
    const bf16 *A, *B; int K, k0;
    if (TWO && t < 4) { A = A0; B = B0; K = K0; k0 = t << 6; }
    else if (TWO)     { A = A1; B = B1; K = K1; k0 = (t - 4) << 6; }
    else              { A = A0; B = B0; K = K0; k0 = t << 6; }
    bf16* base = lds + bsel * 12288;
#pragma unroll
    for (int r = 0; r < 4; ++r)                       // A: wave stages 32 rows
      gload16(&A[(size_t)(m0 + w * 32 + r * 8 + srow) * K + k0 + scol],
              base + (w * 32 + r * 8) * 64);
#pragma unroll
    for (int r = 0; r < 2; ++r)                       // B: wave stages 16 rows
      gload16(&B[(size_t)(n0 + w * 16 + r * 8 + srow) * K + k0 + scol],
              base + 8192 + (w * 16 + r * 8) * 64);
  };

  stage(0, 0); stage(1, 1);
  VMCNT(6);                           // tile 0 landed (per-wave)
  for (int t = 0; t < NT; ++t) {
    MEMFENCE();
    __builtin_amdgcn_s_barrier();     // all waves: tile t landed; buf (t+2)%3 free
    MEMFENCE();
    if (t + 2 < NT) {
      int b = (t + 2) % 3;
      stage(t + 2, b);
      VMCNT(6);                       // tile t+1 landed per-wave
    } else if (t == NT - 2) {
      VMCNT(0);
    }
    const bf16* Ab = lds + (t % 3) * 12288;
    const bf16* Bb = Ab + 8192;
#pragma unroll
    for (int kk = 0; kk < 2; ++kk) {
      bf16x8 af[4], bfr[2];
#pragma unroll
      for (int mi = 0; mi < 4; ++mi) {
        int row = wr * 64 + mi * 16 + lr;
        af[mi] = *(const bf16x8*)&Ab[row * 64 + ((((kk << 2) | lk) ^ (row & 7)) << 3)];
      }
#pragma unroll
      for (int ni = 0; ni < 2; ++ni) {
        int row = wc * 32 + ni * 16 + lr;
        bfr[ni] = *(const bf16x8*)&Bb[row * 64 + ((((kk << 2) | lk) ^ (row & 7)) << 3)];
      }
#pragma unroll
      for (int mi = 0; mi < 4; ++mi)
#pragma unroll
        for (int ni = 0; ni < 2; ++ni)
          acc[mi][ni] = mfma16(af[mi], bfr[ni], acc[mi][ni]);
    }
  }
}

// ---------------- k1: RNN cell ----------------

__global__ __launch_bounds__(256, 2)
void rnn_cell_kernel(const bf16* __restrict__ e,     // [N][EMBD]
                     const bf16* __restrict__ hprev, // [N][HIDN]
                     const bf16* __restrict__ Wih,   // [HIDN][EMBD]
                     const bf16* __restrict__ Whh,   // [HIDN][HIDN]
                     const float* __restrict__ bias, // [HIDN]
                     bf16* __restrict__ hnew)        // [N][HIDN]
{
  __shared__ bf16 lds[3 * 12288];    // 72 KB
  const int tid = threadIdx.x;
  const int lane = tid & 63;
  const int w = tid >> 6;
  const int wr = w >> 1, wc = w & 1;
  const int id = (blockIdx.x & 7) * 64 + (blockIdx.x >> 3);  // 512 blocks, bijective
  const int m0 = (id >> 4) * 128;    // 32 m-tiles
  const int n0 = (id & 15) * 64;     // 16 n-tiles
  const int lr = lane & 15, lk = lane >> 4;

  f32x4 acc[4][2] = {};
  pipe_gemm<true, 20>(e, Wih, EMBD, hprev, Whh, HIDN, lds, m0, n0, w, lane, acc);

#pragma unroll
  for (int mi = 0; mi < 4; ++mi) {
    int rowb = m0 + wr * 64 + mi * 16 + lk * 4;
#pragma unroll
    for (int ni = 0; ni < 2; ++ni) {
      int col = n0 + wc * 32 + ni * 16 + lr;
      float bs = bias[col];
#pragma unroll
      for (int j = 0; j < 4; ++j)
        hnew[(size_t)(rowb + j) * HIDN + col] = (bf16)tanhf(acc[mi][ni][j] + bs);
    }
  }
}

// ---------------- k2: logits = h@Wout^T + b_out -> fp16 scratch ----------------

__global__ __launch_bounds__(256, 2)
void logits_kernel(const bf16* __restrict__ h,    // [N][HIDN]
                   const bf16* __restrict__ Wout, // [VOC][HIDN]
                   const float* __restrict__ bout,
                   h16* __restrict__ lbuf)        // [N][VOC]
{
  __shared__ bf16 lds[3 * 12288];
  const int tid = threadIdx.x;
  const int lane = tid & 63;
  const int w = tid >> 6;
  const int wr = w >> 1, wc = w & 1;
  const int id = (blockIdx.x & 7) * 64 + (blockIdx.x >> 3);
  const int m0 = (id >> 4) * 128;
  const int n0 = (id & 15) * 64;
  const int lr = lane & 15, lk = lane >> 4;

  f32x4 acc[4][2] = {};
  pipe_gemm<false, 16>(h, Wout, HIDN, nullptr, nullptr, 0, lds, m0, n0, w, lane, acc);

#pragma unroll
  for (int mi = 0; mi < 4; ++mi) {
    int rowb = m0 + wr * 64 + mi * 16 + lk * 4;
#pragma unroll
    for (int ni = 0; ni < 2; ++ni) {
      int col = n0 + wc * 32 + ni * 16 + lr;
      float bs = bout[col];
#pragma unroll
      for (int j = 0; j < 4; ++j) {
        int row = rowb + j;
        lbuf[(size_t)row * VOC + col] = (h16)(acc[mi][ni][j] + bs);
      }
    }
  }
}

// ---------------- k3: softmax((l+g)) -> fp32 d_out + e_next = x@Wemb^T + b_emb ----------

__global__ __launch_bounds__(512)
void softmax_emb_kernel(const h16* __restrict__ lbuf,  // [N][VOC]
                        const float* __restrict__ gum, // [N][VOC] (step slice)
                        const bf16* __restrict__ Wemb, // [EMBD][VOC]
                        const float* __restrict__ bemb,
                        float* __restrict__ out,       // [N][NSTEP][VOC]
                        bf16* __restrict__ enext,      // [N][EMBD]
                        int step)
{
  __shared__ bf16 xs[16 * 1032];
  const int tid = threadIdx.x;
  const int lane = tid & 63;
  const int w = tid >> 6;       // 0..7
  const int n0 = blockIdx.x * 16;

  for (int rr = 0; rr < 2; ++rr) {
    int r = w + rr * 8;
    const h16* lrow = lbuf + (size_t)(n0 + r) * VOC;
    const float* grow = gum + (size_t)(n0 + r) * VOC;
    float s[16];
    float m = -1e30f;
#pragma unroll
    for (int i = 0; i < 2; ++i) {
      h16x8 lv = *(const h16x8*)&lrow[i * 512 + lane * 8];
      f32x4 g0 = *(const f32x4*)&grow[i * 512 + lane * 8];
      f32x4 g1 = *(const f32x4*)&grow[i * 512 + lane * 8 + 4];
#pragma unroll
      for (int j = 0; j < 4; ++j) {
        float f0 = (float)lv[j] + g0[j];
        float f1 = (float)lv[4 + j] + g1[j];
        s[i * 8 + j] = f0; s[i * 8 + 4 + j] = f1;
        m = fmaxf(m, fmaxf(f0, f1));
      }
    }
#pragma unroll
    for (int off = 32; off; off >>= 1) m = fmaxf(m, __shfl_xor(m, off));
    float sum = 0.f;
#pragma unroll
    for (int i = 0; i < 16; ++i) { s[i] = __expf(s[i] - m); sum += s[i]; }
#pragma unroll
    for (int off = 32; off; off >>= 1) sum += __shfl_xor(sum, off);
    float inv = 1.0f / sum;
    float* orow = out + ((size_t)(n0 + r) * NSTEP + step) * VOC;
#pragma unroll
    for (int i = 0; i < 2; ++i) {
      f32x4 v0, v1;
      bf16x8 bv;
#pragma unroll
      for (int j = 0; j < 4; ++j) {
        float x0 = s[i * 8 + j] * inv;
        float x1 = s[i * 8 + 4 + j] * inv;
        v0[j] = x0; v1[j] = x1;
        bv[j] = (bf16)x0; bv[4 + j] = (bf16)x1;
      }
      *(f32x4*)&orow[i * 512 + lane * 8] = v0;
      *(f32x4*)&orow[i * 512 + lane * 8 + 4] = v1;
      *(bf16x8*)&xs[r * 1032 + i * 512 + lane * 8] = bv;
    }
  }
  __syncthreads();

  const int lr = lane & 15, lk = lane >> 4;
  f32x4 acc[2] = {};
  for (int k0 = 0; k0 < VOC; k0 += 32) {
    bf16x8 a = *(bf16x8*)&xs[lr * 1032 + k0 + lk * 8];
#pragma unroll
    for (int ni = 0; ni < 2; ++ni) {
      int col = w * 32 + ni * 16 + lr;
      bf16x8 b = *(const bf16x8*)&Wemb[(size_t)col * VOC + k0 + lk * 8];
      acc[ni] = mfma16(a, b, acc[ni]);
    }
  }
#pragma unroll
  for (int ni = 0; ni < 2; ++ni) {
    int col = w * 32 + ni * 16 + lr;
    float bb = bemb[col];
#pragma unroll
    for (int j = 0; j < 4; ++j) {
      int n = n0 + lk * 4 + j;
      enext[(size_t)n * EMBD + col] = (bf16)(acc[ni][j] + bb);
    }
  }
}

// ---------------- launch ----------------

extern "C" void kernel_launch(void* const* d_in, const int* in_sizes, int n_in,
                              void* d_out, int out_size, void* d_ws, size_t ws_size,
                              hipStream_t stream) {
  const float* target  = (const float*)d_in[0];
  const float* gumbels = (const float*)d_in[1];
  const float* sos     = (const float*)d_in[2];
  const float* W_ih    = (const float*)d_in[3];
  const float* b_ih    = (const float*)d_in[4];
  const float* W_hh    = (const float*)d_in[5];
  const float* b_hh    = (const float*)d_in[6];
  const float* W_out   = (const float*)d_in[7];
  const float* b_out   = (const float*)d_in[8];
  const float* W_emb   = (const float*)d_in[9];
  const float* b_emb   = (const float*)d_in[10];
  float* out = (float*)d_out;

  char* ws = (char*)d_ws;
  bf16* wih_b  = (bf16*)(ws);                // 512 KB
  bf16* whh_b  = (bf16*)(ws + (1u << 20));   // 2 MB
  bf16* wout_b = (bf16*)(ws + (3u << 20));   // 2 MB
  bf16* wemb_b = (bf16*)(ws + (5u << 20));   // 512 KB
  float* bias1 = (float*)(ws + (6u << 20));  // 4 KB
  bf16* hbuf0  = (bf16*)(ws + (7u << 20));   // 8 MB
  bf16* hbuf1  = (bf16*)(ws + (15u << 20));  // 8 MB
  bf16* ebuf   = (bf16*)(ws + (23u << 20));  // 2 MB
  h16*  lbuf   = (h16*) (ws + (25u << 20));  // 8 MB

  prep_kernel<<<2048, 256, 0, stream>>>(W_ih, W_hh, W_out, W_emb, target, sos,
                                        b_ih, b_hh, wih_b, whh_b, wout_b, wemb_b,
                                        hbuf0, ebuf, bias1);

  bf16* hb[2] = {hbuf0, hbuf1};
  for (int t = 0; t < NSTEP; ++t) {
    bf16* hp = hb[t & 1];
    bf16* hn = hb[(t + 1) & 1];
    rnn_cell_kernel<<<(N_TOT / 128) * (HIDN / 64), 256, 0, stream>>>(
        ebuf, hp, wih_b, whh_b, bias1, hn);
    logits_kernel<<<(N_TOT / 128) * (VOC / 64), 256, 0, stream>>>(
        hn, wout_b, b_out, lbuf);
    softmax_emb_kernel<<<N_TOT / 16, 512, 0, stream>>>(
        lbuf, gumbels + (size_t)t * N_TOT * VOC, wemb_b, b_emb, out, ebuf, t);
  }
}